// Round 4
// baseline (415.285 us; speedup 1.0000x reference)
//
#include <hip/hip_runtime.h>
#include <stdint.h>

typedef unsigned short u16;
typedef __attribute__((ext_vector_type(8))) short bh8;   // 8 bf16 = 4 VGPR
typedef __attribute__((ext_vector_type(4))) float f4;    // MFMA acc

#define LOG2E 1.44269504088896f
#define QSCALE 0.18033688f   // 0.125 * log2(e), folded into Q at GEMM1 epilogue

__device__ inline u16 f2bf(float f) {
  union { float f; uint32_t u; } c; c.f = f;
  uint32_t u = c.u;
  return (u16)((u + 0x7fffu + ((u >> 16) & 1u)) >> 16);  // RNE
}

__device__ inline float fast_exp2(float x) {
#if __has_builtin(__builtin_amdgcn_exp2f)
  return __builtin_amdgcn_exp2f(x);
#else
  return exp2f(x);
#endif
}

#if __has_builtin(__builtin_amdgcn_global_load_lds)
#define GLD16(gp, lp) __builtin_amdgcn_global_load_lds( \
    (const __attribute__((address_space(1))) void*)(gp), \
    (__attribute__((address_space(3))) void*)(lp), 16, 0, 0)
#else
#define GLD16(gp, lp) do { *(bh8*)(lp) = *(const bh8*)(gp); } while (0)
#endif

#if __has_builtin(__builtin_amdgcn_sched_barrier)
#define SCHED_FENCE() __builtin_amdgcn_sched_barrier(0)
#else
#define SCHED_FENCE() do {} while (0)
#endif

// ---------------- convert / transpose ----------------

__global__ __launch_bounds__(256) void cvt_f32_bf16(const float* __restrict__ src,
                                                    u16* __restrict__ dst, int n4) {
  int i = blockIdx.x * 256 + threadIdx.x;
  if (i < n4) {
    float4 v = ((const float4*)src)[i];
    ushort4 o;
    o.x = f2bf(v.x); o.y = f2bf(v.y); o.z = f2bf(v.z); o.w = f2bf(v.w);
    ((ushort4*)dst)[i] = o;
  }
}

// src: K x N fp32 row-major -> dst: N x K bf16 row-major
__global__ __launch_bounds__(1024) void transpose_cvt(const float* __restrict__ src,
                                                      u16* __restrict__ dst, int K, int N) {
  __shared__ float tile[32][33];
  int n0 = blockIdx.x * 32, k0 = blockIdx.y * 32;
  int tx = threadIdx.x, ty = threadIdx.y;
  tile[ty][tx] = src[(size_t)(k0 + ty) * N + n0 + tx];
  __syncthreads();
  dst[(size_t)(n0 + ty) * K + k0 + tx] = f2bf(tile[tx][ty]);
}

// v [64][2048][64] bf16 -> vt [64][64][2048] bf16
__global__ __launch_bounds__(1024) void transpose_b16(const u16* __restrict__ src,
                                                      u16* __restrict__ dst) {
  __shared__ u16 t[32][33];
  int bh = blockIdx.z, l0 = blockIdx.y * 32, d0 = blockIdx.x * 32;
  int tx = threadIdx.x, ty = threadIdx.y;
  t[ty][tx] = src[((size_t)bh * 2048 + l0 + ty) * 64 + d0 + tx];
  __syncthreads();
  dst[((size_t)bh * 64 + d0 + ty) * 2048 + l0 + tx] = t[tx][ty];
}

// ---------------- GEMM mainloop (C = A @ Bt^T), 128x128 tile, BK=64 ----------------
__device__ inline void gemm_mainloop(const u16* __restrict__ A, const u16* __restrict__ Bt,
                                     int K, int m0, int n0,
                                     u16* As, u16* Bs, f4 acc[4][4]) {
  const int tid  = threadIdx.x;
  const int lane = tid & 63;
  const int quad = lane >> 4;
  const int ml   = lane & 15;
  const int wave = tid >> 6;
  const int wm   = (wave >> 1) * 64;
  const int wn   = (wave & 1) * 64;

#pragma unroll 1
  for (int k0 = 0; k0 < K; k0 += 64) {
#pragma unroll
    for (int r = 0; r < 4; ++r) {
      int chunk = r * 256 + tid;
      int row = chunk >> 3, cc = chunk & 7;
      int cg = cc ^ (row & 7);
      GLD16(A + (size_t)(m0 + row) * K + k0 + cg * 8, As + chunk * 8);
    }
#pragma unroll
    for (int r = 0; r < 4; ++r) {
      int chunk = r * 256 + tid;
      int row = chunk >> 3, cc = chunk & 7;
      int cg = cc ^ (row & 7);
      GLD16(Bt + (size_t)(n0 + row) * K + k0 + cg * 8, Bs + chunk * 8);
    }
    __syncthreads();
#pragma unroll
    for (int ks = 0; ks < 2; ++ks) {
      bh8 af[4], bfr[4];
      int cs = (ks * 4 + quad) ^ (ml & 7);
#pragma unroll
      for (int i = 0; i < 4; ++i) {
        int row = wm + i * 16 + ml;
        af[i] = *(const bh8*)(As + (row * 8 + cs) * 8);
      }
#pragma unroll
      for (int j = 0; j < 4; ++j) {
        int row = wn + j * 16 + ml;
        bfr[j] = *(const bh8*)(Bs + (row * 8 + cs) * 8);
      }
#pragma unroll
      for (int i = 0; i < 4; ++i)
#pragma unroll
        for (int j = 0; j < 4; ++j)
          acc[i][j] = __builtin_amdgcn_mfma_f32_16x16x32_bf16(af[i], bfr[j], acc[i][j], 0, 0, 0);
    }
    __syncthreads();
  }
}

// ---------------- GEMM1: qkv = x @ w_qkv + b ----------------
// q scaled by QSCALE; q,k,v all stored [bh][l][d] bf16 (v transposed later)
__global__ __launch_bounds__(256) void gemm_qkv(const u16* __restrict__ xb,
                                                const u16* __restrict__ wqt,
                                                const float* __restrict__ bqkv,
                                                u16* __restrict__ q, u16* __restrict__ k,
                                                u16* __restrict__ v) {
  __shared__ __align__(16) u16 smem[2 * 128 * 64];
  const f4 fzero = {0.f, 0.f, 0.f, 0.f};
  f4 acc[4][4];
#pragma unroll
  for (int i = 0; i < 4; ++i)
#pragma unroll
    for (int j = 0; j < 4; ++j) acc[i][j] = fzero;

  int m0 = blockIdx.y * 128, n0 = blockIdx.x * 128;
  gemm_mainloop(xb, wqt, 1024, m0, n0, smem, smem + 128 * 64, acc);

  const int lane = threadIdx.x & 63, wave = threadIdx.x >> 6;
  const int quad = lane >> 4, ml = lane & 15;
  const int wm = (wave >> 1) * 64, wn = (wave & 1) * 64;
  u16* dst = (n0 < 1024) ? q : ((n0 < 2048) ? k : v);
  float scale = (n0 < 1024) ? QSCALE : 1.0f;
#pragma unroll
  for (int j = 0; j < 4; ++j) {
    int nn = n0 + wn + j * 16 + ml;
    int h = (nn >> 6) & 15, d = nn & 63;
    float bias = bqkv[nn];
#pragma unroll
    for (int i = 0; i < 4; ++i) {
#pragma unroll
      for (int r = 0; r < 4; ++r) {
        int tok = m0 + wm + i * 16 + quad * 4 + r;
        int b = tok >> 11, l = tok & 2047;
        int bh = b * 16 + h;
        dst[((size_t)bh * 2048 + l) * 64 + d] = f2bf((acc[i][j][r] + bias) * scale);
      }
    }
  }
}

// ---------------- GEMM2: out = o @ w_out + b_out (fp32 out) ----------------
__global__ __launch_bounds__(256) void gemm_out(const u16* __restrict__ ob,
                                                const u16* __restrict__ wot,
                                                const float* __restrict__ bout,
                                                float* __restrict__ out) {
  __shared__ __align__(16) u16 smem[2 * 128 * 64];
  const f4 fzero = {0.f, 0.f, 0.f, 0.f};
  f4 acc[4][4];
#pragma unroll
  for (int i = 0; i < 4; ++i)
#pragma unroll
    for (int j = 0; j < 4; ++j) acc[i][j] = fzero;

  int m0 = blockIdx.y * 128, n0 = blockIdx.x * 128;
  gemm_mainloop(ob, wot, 1024, m0, n0, smem, smem + 128 * 64, acc);

  const int lane = threadIdx.x & 63, wave = threadIdx.x >> 6;
  const int quad = lane >> 4, ml = lane & 15;
  const int wm = (wave >> 1) * 64, wn = (wave & 1) * 64;
#pragma unroll
  for (int j = 0; j < 4; ++j) {
    int nn = n0 + wn + j * 16 + ml;
    float bias = bout[nn];
#pragma unroll
    for (int i = 0; i < 4; ++i)
#pragma unroll
      for (int r = 0; r < 4; ++r) {
        int tok = m0 + wm + i * 16 + quad * 4 + r;
        out[(size_t)tok * 1024 + nn] = acc[i][j][r] + bias;
      }
  }
}

// ---------------- flash attention v7: fix vmcnt issue-order (round-3 postmortem) ---
// v6 regression root cause: vmcnt is an IN-ORDER counter. Issue order was
// [K-stage GLD16] ... [vf global loads], so PV's wait for vf was vmcnt(0), forcing
// the next-tile K staging to complete mid-tile -- the double-buffer pipeline was
// structurally dead. Fix: issue ALL 8 vf loads at the TOP of the loop, BEFORE the
// K-stage GLD16s (pinned with one sched_barrier(0); kp/vp are distinct __restrict__
// so the scheduler may otherwise sink them). PV then waits vmcnt(2): vf data ready,
// K staging stays in flight until the end-of-tile barrier drain (~whole tile of
// cover). V loads get QK+softmax (~300 cyc) of cover vs ~200 cyc L2 latency.
// Cost: vf0+vf1 (32 VGPR) live across QK+softmax -> watch VGPR_Count <= 128.
__global__ __launch_bounds__(256, 4) void attn(const u16* __restrict__ q,
                                               const u16* __restrict__ k,
                                               const u16* __restrict__ vt,
                                               u16* __restrict__ o) {
  __shared__ __align__(16) u16 Ks[2][64 * 64];    // row=key, 8 chunks, XOR swizzle
  __shared__ __align__(16) u16 Pq[4][32 * 64];    // per-wave P [q][key], phase-swizzled
  const int bh = blockIdx.x;
  const int b = bh >> 4, h = bh & 15;
  const int tid = threadIdx.x;
  const int wave = tid >> 6, lane = tid & 63;
  const int quad = lane >> 4, ml = lane & 15;
  const int qw = blockIdx.y * 128 + wave * 32;
  const u16* qp = q + (size_t)bh * 2048 * 64;
  const u16* kp = k + (size_t)bh * 2048 * 64;
  const u16* vp = vt + (size_t)bh * 64 * 2048;
  const f4 fzero = {0.f, 0.f, 0.f, 0.f};

  const int mlx = ml & 7;          // XOR bits for 16B-unit swizzle
  const bool mlh = (ml & 8) != 0;  // half-swap bit
  const int hb = (((quad & 1) ^ (mlh ? 1 : 0)) << 2);  // half offset in u16 units
  const int qv = quad >> 1;

  // Q fragments: B-operand, rows qw+g*16+ml, 16B contiguous
  bh8 qf[2][2];
#pragma unroll
  for (int g = 0; g < 2; ++g)
#pragma unroll
    for (int ks = 0; ks < 2; ++ks)
      qf[g][ks] = *(const bh8*)&qp[(size_t)(qw + g * 16 + ml) * 64 + ks * 32 + quad * 8];

  f4 oacc[2][4];
#pragma unroll
  for (int g = 0; g < 2; ++g)
#pragma unroll
    for (int j = 0; j < 4; ++j) oacc[g][j] = fzero;
  float lsum[2] = {0.f, 0.f};

  // K staging addresses (row/chunk decomposition identical to gemm_mainloop)
  const int srow = tid >> 3, scc = tid & 7;
  const int scg = scc ^ (srow & 7);
  u16* pq = &Pq[wave][ml * 64];

  // prologue: stage K tile 0 into buffer 0
#pragma unroll
  for (int r = 0; r < 2; ++r) {
    int row = r * 32 + srow;
    GLD16(kp + (size_t)row * 64 + scg * 8, &Ks[0][(row * 8 + scc) * 8]);
  }
  __syncthreads();

  int cur = 0;
#pragma unroll 1
  for (int t = 0; t < 32; ++t) {
    const int kt = t * 64;

    // V fragments FIRST (A-operand: V^T[d=16j+ml][keys], contiguous 16B runs).
    // Must be issued before the K-stage GLD16s so PV's vmcnt wait leaves the
    // staging in flight (vmcnt is in-order!).
    bh8 vf0[4], vf1[4];
#pragma unroll
    for (int j = 0; j < 4; ++j) {
      const u16* vrow = vp + (size_t)(j * 16 + ml) * 2048 + kt + quad * 8;
      vf0[j] = *(const bh8*)vrow;
      vf1[j] = *(const bh8*)(vrow + 32);
    }
    SCHED_FENCE();  // pin: vf issues stay above the staging below

    // stage next K tile (in flight until end-of-tile barrier drain)
    if (t < 31) {
      int ktn = kt + 64;
#pragma unroll
      for (int r = 0; r < 2; ++r) {
        int row = r * 32 + srow;
        GLD16(kp + (size_t)(ktn + row) * 64 + scg * 8, &Ks[cur ^ 1][(row * 8 + scc) * 8]);
      }
    }

    // S^T = K @ Q^T from LDS: s[g][j][r] = S[q=qw+g*16+ml][kt + 16j + 4quad + r]
    f4 s[2][4];
#pragma unroll
    for (int g = 0; g < 2; ++g)
#pragma unroll
      for (int j = 0; j < 4; ++j) s[g][j] = fzero;
#pragma unroll
    for (int ks = 0; ks < 2; ++ks) {
      int cs = (ks * 4 + quad) ^ mlx;
      bh8 kf[4];
#pragma unroll
      for (int j = 0; j < 4; ++j)
        kf[j] = *(const bh8*)(&Ks[cur][((j * 16 + ml) * 8 + cs) * 8]);
#pragma unroll
      for (int j = 0; j < 4; ++j) {
        s[0][j] = __builtin_amdgcn_mfma_f32_16x16x32_bf16(kf[j], qf[0][ks], s[0][j], 0, 0, 0);
        s[1][j] = __builtin_amdgcn_mfma_f32_16x16x32_bf16(kf[j], qf[1][ks], s[1][j], 0, 0, 0);
      }
    }

    // p = exp2(s) -> bf16 RN; accumulate row-sum from the SAME rounded values;
    // write one 8B granule (4 keys) per (g,j): unit v=2j+qv swizzled by ml.
#pragma unroll
    for (int g = 0; g < 2; ++g) {
#pragma unroll
      for (int j = 0; j < 4; ++j) {
        uint32_t w[4];
#pragma unroll
        for (int r = 0; r < 4; ++r) {
          float p = fast_exp2(s[g][j][r]);
          union { float f; uint32_t u; } c; c.f = p;
          c.u = (c.u + 0x8000u) & 0xFFFF0000u;
          lsum[g] += c.f;
          w[r] = c.u;
        }
        uint2 pk;
        pk.x = (w[0] >> 16) | (w[1] & 0xFFFF0000u);
        pk.y = (w[2] >> 16) | (w[3] & 0xFFFF0000u);
        *(uint2*)(pq + g * 1024 + (((2 * j + qv) ^ mlx) << 3) + hb) = pk;
      }
    }

    // O^T += V^T @ P^T ; P fragment = one b128 per (g,ks), half-swap fix via cndmask
#pragma unroll
    for (int ks = 0; ks < 2; ++ks) {
#pragma unroll
      for (int g = 0; g < 2; ++g) {
        union { uint4 u; bh8 v; } pf;
        uint4 tp = *(const uint4*)(pq + g * 1024 + (((4 * ks + quad) ^ mlx) << 3));
        pf.u.x = mlh ? tp.z : tp.x;
        pf.u.y = mlh ? tp.w : tp.y;
        pf.u.z = mlh ? tp.x : tp.z;
        pf.u.w = mlh ? tp.y : tp.w;
#pragma unroll
        for (int j = 0; j < 4; ++j) {
          const bh8 vfj = ks ? vf1[j] : vf0[j];
          oacc[g][j] = __builtin_amdgcn_mfma_f32_16x16x32_bf16(vfj, pf.v, oacc[g][j], 0, 0, 0);
        }
      }
    }
    __syncthreads();   // drains K stage (vmcnt) + all LDS reads of Ks[cur]
    cur ^= 1;
  }

  // li: lane-local partial covers keys {16j+4quad+r}; reduce across quads
#pragma unroll
  for (int g = 0; g < 2; ++g) {
    lsum[g] += __shfl_xor(lsum[g], 16, 64);
    lsum[g] += __shfl_xor(lsum[g], 32, 64);
    float inv = 1.0f / lsum[g];
    // store o as (b, l, h, d) bf16; lane holds q=qw+g*16+ml, d=16j+4quad+r
    size_t obase = (((size_t)b * 2048 + qw + g * 16 + ml) * 16 + h) * 64;
#pragma unroll
    for (int j = 0; j < 4; ++j) {
      ushort4 w;
      w.x = f2bf(oacc[g][j][0] * inv);
      w.y = f2bf(oacc[g][j][1] * inv);
      w.z = f2bf(oacc[g][j][2] * inv);
      w.w = f2bf(oacc[g][j][3] * inv);
      *(ushort4*)(o + obase + j * 16 + quad * 4) = w;
    }
  }
}

// ---------------- launch ----------------

extern "C" void kernel_launch(void* const* d_in, const int* in_sizes, int n_in,
                              void* d_out, int out_size, void* d_ws, size_t ws_size,
                              hipStream_t stream) {
  const float* x     = (const float*)d_in[0];
  const float* w_qkv = (const float*)d_in[1];
  const float* b_qkv = (const float*)d_in[2];
  const float* w_out = (const float*)d_in[3];
  const float* b_out = (const float*)d_in[4];
  float* out = (float*)d_out;

  u16* ws  = (u16*)d_ws;
  u16* xb  = ws;                                  // 8192*1024 (later reused for vt)
  u16* wqt = xb + (size_t)8192 * 1024;            // 3072*1024
  u16* wot = wqt + (size_t)3072 * 1024;           // 1024*1024
  u16* qb  = wot + (size_t)1024 * 1024;           // 64*2048*64
  u16* kb  = qb + (size_t)64 * 2048 * 64;
  u16* vb  = kb + (size_t)64 * 2048 * 64;
  u16* vtb = xb;   // xb dead after gemm_qkv
  u16* ob  = vb;   // v dead after transpose_b16

  cvt_f32_bf16<<<8192, 256, 0, stream>>>(x, xb, 8192 * 1024 / 4);
  transpose_cvt<<<dim3(96, 32), dim3(32, 32), 0, stream>>>(w_qkv, wqt, 1024, 3072);
  transpose_cvt<<<dim3(32, 32), dim3(32, 32), 0, stream>>>(w_out, wot, 1024, 1024);
  gemm_qkv<<<dim3(24, 64), 256, 0, stream>>>(xb, wqt, b_qkv, qb, kb, vb);
  transpose_b16<<<dim3(2, 64, 64), dim3(32, 32), 0, stream>>>(vb, vtb);
  attn<<<dim3(64, 16), 256, 0, stream>>>(qb, kb, vtb, ob);
  gemm_out<<<dim3(8, 64), 256, 0, stream>>>(ob, wot, b_out, out);
}

// Round 6
// 302.814 us; speedup vs baseline: 1.3714x; 1.3714x over previous
//
#include <hip/hip_runtime.h>
#include <stdint.h>

typedef unsigned short u16;
typedef __attribute__((ext_vector_type(8))) short bh8;   // 8 bf16 = 4 VGPR
typedef __attribute__((ext_vector_type(4))) float f4;    // MFMA acc

#define LOG2E 1.44269504088896f
#define QSCALE 0.18033688f   // 0.125 * log2(e), folded into Q at GEMM1 epilogue

__device__ inline u16 f2bf(float f) {
  union { float f; uint32_t u; } c; c.f = f;
  uint32_t u = c.u;
  return (u16)((u + 0x7fffu + ((u >> 16) & 1u)) >> 16);  // RNE
}

__device__ inline float fast_exp2(float x) {
#if __has_builtin(__builtin_amdgcn_exp2f)
  return __builtin_amdgcn_exp2f(x);
#else
  return exp2f(x);
#endif
}

#if __has_builtin(__builtin_amdgcn_global_load_lds)
#define GLD16(gp, lp) __builtin_amdgcn_global_load_lds( \
    (const __attribute__((address_space(1))) void*)(gp), \
    (__attribute__((address_space(3))) void*)(lp), 16, 0, 0)
#else
#define GLD16(gp, lp) do { *(bh8*)(lp) = *(const bh8*)(gp); } while (0)
#endif

// ---------------- convert / transpose ----------------

__global__ __launch_bounds__(256) void cvt_f32_bf16(const float* __restrict__ src,
                                                    u16* __restrict__ dst, int n4) {
  int i = blockIdx.x * 256 + threadIdx.x;
  if (i < n4) {
    float4 v = ((const float4*)src)[i];
    ushort4 o;
    o.x = f2bf(v.x); o.y = f2bf(v.y); o.z = f2bf(v.z); o.w = f2bf(v.w);
    ((ushort4*)dst)[i] = o;
  }
}

// src: K x N fp32 row-major -> dst: N x K bf16 row-major
__global__ __launch_bounds__(1024) void transpose_cvt(const float* __restrict__ src,
                                                      u16* __restrict__ dst, int K, int N) {
  __shared__ float tile[32][33];
  int n0 = blockIdx.x * 32, k0 = blockIdx.y * 32;
  int tx = threadIdx.x, ty = threadIdx.y;
  tile[ty][tx] = src[(size_t)(k0 + ty) * N + n0 + tx];
  __syncthreads();
  dst[(size_t)(n0 + ty) * K + k0 + tx] = f2bf(tile[tx][ty]);
}

// v [64][2048][64] bf16 -> vt [64][64][2048] bf16
__global__ __launch_bounds__(1024) void transpose_b16(const u16* __restrict__ src,
                                                      u16* __restrict__ dst) {
  __shared__ u16 t[32][33];
  int bh = blockIdx.z, l0 = blockIdx.y * 32, d0 = blockIdx.x * 32;
  int tx = threadIdx.x, ty = threadIdx.y;
  t[ty][tx] = src[((size_t)bh * 2048 + l0 + ty) * 64 + d0 + tx];
  __syncthreads();
  dst[((size_t)bh * 64 + d0 + ty) * 2048 + l0 + tx] = t[tx][ty];
}

// ---------------- GEMM mainloop (C = A @ Bt^T), 128x128 tile, BK=64 ----------------
__device__ inline void gemm_mainloop(const u16* __restrict__ A, const u16* __restrict__ Bt,
                                     int K, int m0, int n0,
                                     u16* As, u16* Bs, f4 acc[4][4]) {
  const int tid  = threadIdx.x;
  const int lane = tid & 63;
  const int quad = lane >> 4;
  const int ml   = lane & 15;
  const int wave = tid >> 6;
  const int wm   = (wave >> 1) * 64;
  const int wn   = (wave & 1) * 64;

#pragma unroll 1
  for (int k0 = 0; k0 < K; k0 += 64) {
#pragma unroll
    for (int r = 0; r < 4; ++r) {
      int chunk = r * 256 + tid;
      int row = chunk >> 3, cc = chunk & 7;
      int cg = cc ^ (row & 7);
      GLD16(A + (size_t)(m0 + row) * K + k0 + cg * 8, As + chunk * 8);
    }
#pragma unroll
    for (int r = 0; r < 4; ++r) {
      int chunk = r * 256 + tid;
      int row = chunk >> 3, cc = chunk & 7;
      int cg = cc ^ (row & 7);
      GLD16(Bt + (size_t)(n0 + row) * K + k0 + cg * 8, Bs + chunk * 8);
    }
    __syncthreads();
#pragma unroll
    for (int ks = 0; ks < 2; ++ks) {
      bh8 af[4], bfr[4];
      int cs = (ks * 4 + quad) ^ (ml & 7);
#pragma unroll
      for (int i = 0; i < 4; ++i) {
        int row = wm + i * 16 + ml;
        af[i] = *(const bh8*)(As + (row * 8 + cs) * 8);
      }
#pragma unroll
      for (int j = 0; j < 4; ++j) {
        int row = wn + j * 16 + ml;
        bfr[j] = *(const bh8*)(Bs + (row * 8 + cs) * 8);
      }
#pragma unroll
      for (int i = 0; i < 4; ++i)
#pragma unroll
        for (int j = 0; j < 4; ++j)
          acc[i][j] = __builtin_amdgcn_mfma_f32_16x16x32_bf16(af[i], bfr[j], acc[i][j], 0, 0, 0);
    }
    __syncthreads();
  }
}

// ---------------- GEMM1: qkv = x @ w_qkv + b ----------------
// q scaled by QSCALE; q,k,v all stored [bh][l][d] bf16 (v transposed later)
__global__ __launch_bounds__(256) void gemm_qkv(const u16* __restrict__ xb,
                                                const u16* __restrict__ wqt,
                                                const float* __restrict__ bqkv,
                                                u16* __restrict__ q, u16* __restrict__ k,
                                                u16* __restrict__ v) {
  __shared__ __align__(16) u16 smem[2 * 128 * 64];
  const f4 fzero = {0.f, 0.f, 0.f, 0.f};
  f4 acc[4][4];
#pragma unroll
  for (int i = 0; i < 4; ++i)
#pragma unroll
    for (int j = 0; j < 4; ++j) acc[i][j] = fzero;

  int m0 = blockIdx.y * 128, n0 = blockIdx.x * 128;
  gemm_mainloop(xb, wqt, 1024, m0, n0, smem, smem + 128 * 64, acc);

  const int lane = threadIdx.x & 63, wave = threadIdx.x >> 6;
  const int quad = lane >> 4, ml = lane & 15;
  const int wm = (wave >> 1) * 64, wn = (wave & 1) * 64;
  u16* dst = (n0 < 1024) ? q : ((n0 < 2048) ? k : v);
  float scale = (n0 < 1024) ? QSCALE : 1.0f;
#pragma unroll
  for (int j = 0; j < 4; ++j) {
    int nn = n0 + wn + j * 16 + ml;
    int h = (nn >> 6) & 15, d = nn & 63;
    float bias = bqkv[nn];
#pragma unroll
    for (int i = 0; i < 4; ++i) {
#pragma unroll
      for (int r = 0; r < 4; ++r) {
        int tok = m0 + wm + i * 16 + quad * 4 + r;
        int b = tok >> 11, l = tok & 2047;
        int bh = b * 16 + h;
        dst[((size_t)bh * 2048 + l) * 64 + d] = f2bf((acc[i][j][r] + bias) * scale);
      }
    }
  }
}

// ---------------- GEMM2: out = o @ w_out + b_out (fp32 out) ----------------
__global__ __launch_bounds__(256) void gemm_out(const u16* __restrict__ ob,
                                                const u16* __restrict__ wot,
                                                const float* __restrict__ bout,
                                                float* __restrict__ out) {
  __shared__ __align__(16) u16 smem[2 * 128 * 64];
  const f4 fzero = {0.f, 0.f, 0.f, 0.f};
  f4 acc[4][4];
#pragma unroll
  for (int i = 0; i < 4; ++i)
#pragma unroll
    for (int j = 0; j < 4; ++j) acc[i][j] = fzero;

  int m0 = blockIdx.y * 128, n0 = blockIdx.x * 128;
  gemm_mainloop(ob, wot, 1024, m0, n0, smem, smem + 128 * 64, acc);

  const int lane = threadIdx.x & 63, wave = threadIdx.x >> 6;
  const int quad = lane >> 4, ml = lane & 15;
  const int wm = (wave >> 1) * 64, wn = (wave & 1) * 64;
#pragma unroll
  for (int j = 0; j < 4; ++j) {
    int nn = n0 + wn + j * 16 + ml;
    float bias = bout[nn];
#pragma unroll
    for (int i = 0; i < 4; ++i)
#pragma unroll
      for (int r = 0; r < 4; ++r) {
        int tok = m0 + wm + i * 16 + quad * 4 + r;
        out[(size_t)tok * 1024 + nn] = acc[i][j][r] + bias;
      }
  }
}

// ---------------- flash attention v8 (resubmit: round-5 bench was infra flake) -----
// v8 = v5's proven all-LDS double-buffered skeleton (121us, 0 spills) plus the two
// deltas that were each hardware-validated in v6/v7:
//  1. 2 Q-groups per wave (32 q-rows): the SAME kf/vf LDS reads feed 2x the output
//     -> K/V LDS-read traffic per q-row halves (v5's wall was LDS ~103% busy).
//  2. Phase-aware P swizzle (measured 0 conflicts vs v5's 4.19M).
// LDS model per block-tile (128 q-rows): stage 128 + 4 waves*(kf 96 + vf 96 + pf 48
// + pwrite 48) = 1280 cyc -> 10 cyc/q-row vs v5's ~16.7. Per CU: 128 block-tiles
// -> 164K cyc = 68us floor, ~80us expected.
// LDS = Ks 16K + Vs 16K + Pq 16K = 48KB -> 3 blocks/CU (12 waves). Registers:
// accum half = s(32)+oacc(32)=64 exactly; arch peak ~60 < 64 (less than v6 which fit).
// grid (64 bh, 16 qtiles): bh-major keeps each head's K/V on one XCD's L2.
__global__ __launch_bounds__(256, 4) void attn(const u16* __restrict__ q,
                                               const u16* __restrict__ k,
                                               const u16* __restrict__ vt,
                                               u16* __restrict__ o) {
  __shared__ __align__(16) u16 Ks[2][64 * 64];    // row=key, 8 chunks, XOR swizzle
  __shared__ __align__(16) u16 Vs[2][64 * 64];    // row=d,   cols=key, XOR swizzle
  __shared__ __align__(16) u16 Pq[4][32 * 64];    // per-wave P [q][key], phase-swizzled
  const int bh = blockIdx.x;
  const int b = bh >> 4, h = bh & 15;
  const int tid = threadIdx.x;
  const int wave = tid >> 6, lane = tid & 63;
  const int quad = lane >> 4, ml = lane & 15;
  const int qw = blockIdx.y * 128 + wave * 32;
  const u16* qp = q + (size_t)bh * 2048 * 64;
  const u16* kp = k + (size_t)bh * 2048 * 64;
  const u16* vp = vt + (size_t)bh * 64 * 2048;
  const f4 fzero = {0.f, 0.f, 0.f, 0.f};

  const int mlx = ml & 7;          // XOR bits for 16B-unit swizzle
  const bool mlh = (ml & 8) != 0;  // half-swap bit
  const int hb = (((quad & 1) ^ (mlh ? 1 : 0)) << 2);  // half offset in u16 units
  const int qv = quad >> 1;

  // Q fragments: B-operand, rows qw+g*16+ml, 16B contiguous
  bh8 qf[2][2];
#pragma unroll
  for (int g = 0; g < 2; ++g)
#pragma unroll
    for (int ks = 0; ks < 2; ++ks)
      qf[g][ks] = *(const bh8*)&qp[(size_t)(qw + g * 16 + ml) * 64 + ks * 32 + quad * 8];

  f4 oacc[2][4];
#pragma unroll
  for (int g = 0; g < 2; ++g)
#pragma unroll
    for (int j = 0; j < 4; ++j) oacc[g][j] = fzero;
  float lsum[2] = {0.f, 0.f};

  // staging addresses (row/chunk decomposition identical to gemm_mainloop)
  const int srow = tid >> 3, scc = tid & 7;
  const int scg = scc ^ (srow & 7);
  u16* pq = &Pq[wave][ml * 64];

  // prologue: stage K+V tile 0 into buffer 0
#pragma unroll
  for (int r = 0; r < 2; ++r) {
    int row = r * 32 + srow;
    GLD16(kp + (size_t)row * 64 + scg * 8, &Ks[0][(row * 8 + scc) * 8]);
    GLD16(vp + (size_t)row * 2048 + scg * 8, &Vs[0][(row * 8 + scc) * 8]);
  }
  __syncthreads();

  int cur = 0;
#pragma unroll 1
  for (int t = 0; t < 32; ++t) {
    // stage next K+V tile into the other buffer (in flight until end-of-tile drain)
    if (t < 31) {
      int ktn = (t + 1) * 64;
#pragma unroll
      for (int r = 0; r < 2; ++r) {
        int row = r * 32 + srow;
        GLD16(kp + (size_t)(ktn + row) * 64 + scg * 8, &Ks[cur ^ 1][(row * 8 + scc) * 8]);
        GLD16(vp + (size_t)row * 2048 + ktn + scg * 8, &Vs[cur ^ 1][(row * 8 + scc) * 8]);
      }
    }

    // S^T = K @ Q^T from LDS: s[g][j][r] = S[q=qw+g*16+ml][kt + 16j + 4quad + r]
    f4 s[2][4];
#pragma unroll
    for (int g = 0; g < 2; ++g)
#pragma unroll
      for (int j = 0; j < 4; ++j) s[g][j] = fzero;
#pragma unroll
    for (int ks = 0; ks < 2; ++ks) {
      int cs = (ks * 4 + quad) ^ mlx;
      bh8 kf[4];
#pragma unroll
      for (int j = 0; j < 4; ++j)
        kf[j] = *(const bh8*)(&Ks[cur][((j * 16 + ml) * 8 + cs) * 8]);
#pragma unroll
      for (int j = 0; j < 4; ++j) {
        s[0][j] = __builtin_amdgcn_mfma_f32_16x16x32_bf16(kf[j], qf[0][ks], s[0][j], 0, 0, 0);
        s[1][j] = __builtin_amdgcn_mfma_f32_16x16x32_bf16(kf[j], qf[1][ks], s[1][j], 0, 0, 0);
      }
    }

    // p = exp2(s) -> bf16 RN; accumulate row-sum from the SAME rounded values;
    // write one 8B granule (4 keys) per (g,j): unit 2j+qv swizzled by ml (0 conflicts).
#pragma unroll
    for (int g = 0; g < 2; ++g) {
#pragma unroll
      for (int j = 0; j < 4; ++j) {
        uint32_t w[4];
#pragma unroll
        for (int r = 0; r < 4; ++r) {
          float p = fast_exp2(s[g][j][r]);
          union { float f; uint32_t u; } c; c.f = p;
          c.u = (c.u + 0x8000u) & 0xFFFF0000u;
          lsum[g] += c.f;
          w[r] = c.u;
        }
        uint2 pk;
        pk.x = (w[0] >> 16) | (w[1] & 0xFFFF0000u);
        pk.y = (w[2] >> 16) | (w[3] & 0xFFFF0000u);
        *(uint2*)(pq + g * 1024 + (((2 * j + qv) ^ mlx) << 3) + hb) = pk;
      }
    }

    // O^T += V^T @ P^T: vf from LDS (read once per ks, reused for both groups);
    // P fragment = one b128 per (g,ks), half-swap fix via cndmask.
#pragma unroll
    for (int ks = 0; ks < 2; ++ks) {
      int cs = (ks * 4 + quad) ^ mlx;
      bh8 vf[4];
#pragma unroll
      for (int j = 0; j < 4; ++j)
        vf[j] = *(const bh8*)(&Vs[cur][((j * 16 + ml) * 8 + cs) * 8]);
#pragma unroll
      for (int g = 0; g < 2; ++g) {
        union { uint4 u; bh8 v; } pf;
        uint4 tp = *(const uint4*)(pq + g * 1024 + (((4 * ks + quad) ^ mlx) << 3));
        pf.u.x = mlh ? tp.z : tp.x;
        pf.u.y = mlh ? tp.w : tp.y;
        pf.u.z = mlh ? tp.x : tp.z;
        pf.u.w = mlh ? tp.y : tp.w;
#pragma unroll
        for (int j = 0; j < 4; ++j)
          oacc[g][j] = __builtin_amdgcn_mfma_f32_16x16x32_bf16(vf[j], pf.v, oacc[g][j], 0, 0, 0);
      }
    }
    __syncthreads();   // drains K/V stage (vmcnt) + all LDS reads of buf[cur]
    cur ^= 1;
  }

  // li: lane-local partial covers keys {16j+4quad+r}; reduce across quads
#pragma unroll
  for (int g = 0; g < 2; ++g) {
    lsum[g] += __shfl_xor(lsum[g], 16, 64);
    lsum[g] += __shfl_xor(lsum[g], 32, 64);
    float inv = 1.0f / lsum[g];
    // store o as (b, l, h, d) bf16; lane holds q=qw+g*16+ml, d=16j+4quad+r
    size_t obase = (((size_t)b * 2048 + qw + g * 16 + ml) * 16 + h) * 64;
#pragma unroll
    for (int j = 0; j < 4; ++j) {
      ushort4 w;
      w.x = f2bf(oacc[g][j][0] * inv);
      w.y = f2bf(oacc[g][j][1] * inv);
      w.z = f2bf(oacc[g][j][2] * inv);
      w.w = f2bf(oacc[g][j][3] * inv);
      *(ushort4*)(o + obase + j * 16 + quad * 4) = w;
    }
  }
}

// ---------------- launch ----------------

extern "C" void kernel_launch(void* const* d_in, const int* in_sizes, int n_in,
                              void* d_out, int out_size, void* d_ws, size_t ws_size,
                              hipStream_t stream) {
  const float* x     = (const float*)d_in[0];
  const float* w_qkv = (const float*)d_in[1];
  const float* b_qkv = (const float*)d_in[2];
  const float* w_out = (const float*)d_in[3];
  const float* b_out = (const float*)d_in[4];
  float* out = (float*)d_out;

  u16* ws  = (u16*)d_ws;
  u16* xb  = ws;                                  // 8192*1024 (later reused for vt)
  u16* wqt = xb + (size_t)8192 * 1024;            // 3072*1024
  u16* wot = wqt + (size_t)3072 * 1024;           // 1024*1024
  u16* qb  = wot + (size_t)1024 * 1024;           // 64*2048*64
  u16* kb  = qb + (size_t)64 * 2048 * 64;
  u16* vb  = kb + (size_t)64 * 2048 * 64;
  u16* vtb = xb;   // xb dead after gemm_qkv
  u16* ob  = vb;   // v dead after transpose_b16

  cvt_f32_bf16<<<8192, 256, 0, stream>>>(x, xb, 8192 * 1024 / 4);
  transpose_cvt<<<dim3(96, 32), dim3(32, 32), 0, stream>>>(w_qkv, wqt, 1024, 3072);
  transpose_cvt<<<dim3(32, 32), dim3(32, 32), 0, stream>>>(w_out, wot, 1024, 1024);
  gemm_qkv<<<dim3(24, 64), 256, 0, stream>>>(xb, wqt, b_qkv, qb, kb, vb);
  transpose_b16<<<dim3(2, 64, 64), dim3(32, 32), 0, stream>>>(vb, vtb);
  attn<<<dim3(64, 16), 256, 0, stream>>>(qb, kb, vtb, ob);
  gemm_out<<<dim3(8, 64), 256, 0, stream>>>(ob, wot, b_out, out);
}

// Round 8
// 289.309 us; speedup vs baseline: 1.4354x; 1.0467x over previous
//
#include <hip/hip_runtime.h>
#include <stdint.h>

typedef unsigned short u16;
typedef __attribute__((ext_vector_type(8))) short bh8;   // 8 bf16 = 4 VGPR
typedef __attribute__((ext_vector_type(4))) float f4;    // MFMA acc

#define LOG2E 1.44269504088896f
#define QSCALE 0.18033688f   // 0.125 * log2(e), folded into Q at GEMM1 epilogue

__device__ inline u16 f2bf(float f) {
  union { float f; uint32_t u; } c; c.f = f;
  uint32_t u = c.u;
  return (u16)((u + 0x7fffu + ((u >> 16) & 1u)) >> 16);  // RNE
}

__device__ inline float fast_exp2(float x) {
#if __has_builtin(__builtin_amdgcn_exp2f)
  return __builtin_amdgcn_exp2f(x);
#else
  return exp2f(x);
#endif
}

#if __has_builtin(__builtin_amdgcn_global_load_lds)
#define GLD16(gp, lp) __builtin_amdgcn_global_load_lds( \
    (const __attribute__((address_space(1))) void*)(gp), \
    (__attribute__((address_space(3))) void*)(lp), 16, 0, 0)
#else
#define GLD16(gp, lp) do { *(bh8*)(lp) = *(const bh8*)(gp); } while (0)
#endif

// ---------------- convert / transpose ----------------

__global__ __launch_bounds__(256) void cvt_f32_bf16(const float* __restrict__ src,
                                                    u16* __restrict__ dst, int n4) {
  int i = blockIdx.x * 256 + threadIdx.x;
  if (i < n4) {
    float4 v = ((const float4*)src)[i];
    ushort4 o;
    o.x = f2bf(v.x); o.y = f2bf(v.y); o.z = f2bf(v.z); o.w = f2bf(v.w);
    ((ushort4*)dst)[i] = o;
  }
}

// src: K x N fp32 row-major -> dst: N x K bf16 row-major
__global__ __launch_bounds__(1024) void transpose_cvt(const float* __restrict__ src,
                                                      u16* __restrict__ dst, int K, int N) {
  __shared__ float tile[32][33];
  int n0 = blockIdx.x * 32, k0 = blockIdx.y * 32;
  int tx = threadIdx.x, ty = threadIdx.y;
  tile[ty][tx] = src[(size_t)(k0 + ty) * N + n0 + tx];
  __syncthreads();
  dst[(size_t)(n0 + ty) * K + k0 + tx] = f2bf(tile[tx][ty]);
}

// v [64][2048][64] bf16 -> vt [64][64][2048] bf16
__global__ __launch_bounds__(1024) void transpose_b16(const u16* __restrict__ src,
                                                      u16* __restrict__ dst) {
  __shared__ u16 t[32][33];
  int bh = blockIdx.z, l0 = blockIdx.y * 32, d0 = blockIdx.x * 32;
  int tx = threadIdx.x, ty = threadIdx.y;
  t[ty][tx] = src[((size_t)bh * 2048 + l0 + ty) * 64 + d0 + tx];
  __syncthreads();
  dst[((size_t)bh * 64 + d0 + ty) * 2048 + l0 + tx] = t[tx][ty];
}

// ---------------- GEMM mainloop (C = A @ Bt^T), 128x128 tile, BK=64 ----------------
__device__ inline void gemm_mainloop(const u16* __restrict__ A, const u16* __restrict__ Bt,
                                     int K, int m0, int n0,
                                     u16* As, u16* Bs, f4 acc[4][4]) {
  const int tid  = threadIdx.x;
  const int lane = tid & 63;
  const int quad = lane >> 4;
  const int ml   = lane & 15;
  const int wave = tid >> 6;
  const int wm   = (wave >> 1) * 64;
  const int wn   = (wave & 1) * 64;

#pragma unroll 1
  for (int k0 = 0; k0 < K; k0 += 64) {
#pragma unroll
    for (int r = 0; r < 4; ++r) {
      int chunk = r * 256 + tid;
      int row = chunk >> 3, cc = chunk & 7;
      int cg = cc ^ (row & 7);
      GLD16(A + (size_t)(m0 + row) * K + k0 + cg * 8, As + chunk * 8);
    }
#pragma unroll
    for (int r = 0; r < 4; ++r) {
      int chunk = r * 256 + tid;
      int row = chunk >> 3, cc = chunk & 7;
      int cg = cc ^ (row & 7);
      GLD16(Bt + (size_t)(n0 + row) * K + k0 + cg * 8, Bs + chunk * 8);
    }
    __syncthreads();
#pragma unroll
    for (int ks = 0; ks < 2; ++ks) {
      bh8 af[4], bfr[4];
      int cs = (ks * 4 + quad) ^ (ml & 7);
#pragma unroll
      for (int i = 0; i < 4; ++i) {
        int row = wm + i * 16 + ml;
        af[i] = *(const bh8*)(As + (row * 8 + cs) * 8);
      }
#pragma unroll
      for (int j = 0; j < 4; ++j) {
        int row = wn + j * 16 + ml;
        bfr[j] = *(const bh8*)(Bs + (row * 8 + cs) * 8);
      }
#pragma unroll
      for (int i = 0; i < 4; ++i)
#pragma unroll
        for (int j = 0; j < 4; ++j)
          acc[i][j] = __builtin_amdgcn_mfma_f32_16x16x32_bf16(af[i], bfr[j], acc[i][j], 0, 0, 0);
    }
    __syncthreads();
  }
}

// ---------------- GEMM1: qkv = x @ w_qkv + b ----------------
// q scaled by QSCALE; q,k,v all stored [bh][l][d] bf16 (v transposed later)
__global__ __launch_bounds__(256) void gemm_qkv(const u16* __restrict__ xb,
                                                const u16* __restrict__ wqt,
                                                const float* __restrict__ bqkv,
                                                u16* __restrict__ q, u16* __restrict__ k,
                                                u16* __restrict__ v) {
  __shared__ __align__(16) u16 smem[2 * 128 * 64];
  const f4 fzero = {0.f, 0.f, 0.f, 0.f};
  f4 acc[4][4];
#pragma unroll
  for (int i = 0; i < 4; ++i)
#pragma unroll
    for (int j = 0; j < 4; ++j) acc[i][j] = fzero;

  int m0 = blockIdx.y * 128, n0 = blockIdx.x * 128;
  gemm_mainloop(xb, wqt, 1024, m0, n0, smem, smem + 128 * 64, acc);

  const int lane = threadIdx.x & 63, wave = threadIdx.x >> 6;
  const int quad = lane >> 4, ml = lane & 15;
  const int wm = (wave >> 1) * 64, wn = (wave & 1) * 64;
  u16* dst = (n0 < 1024) ? q : ((n0 < 2048) ? k : v);
  float scale = (n0 < 1024) ? QSCALE : 1.0f;
#pragma unroll
  for (int j = 0; j < 4; ++j) {
    int nn = n0 + wn + j * 16 + ml;
    int h = (nn >> 6) & 15, d = nn & 63;
    float bias = bqkv[nn];
#pragma unroll
    for (int i = 0; i < 4; ++i) {
#pragma unroll
      for (int r = 0; r < 4; ++r) {
        int tok = m0 + wm + i * 16 + quad * 4 + r;
        int b = tok >> 11, l = tok & 2047;
        int bh = b * 16 + h;
        dst[((size_t)bh * 2048 + l) * 64 + d] = f2bf((acc[i][j][r] + bias) * scale);
      }
    }
  }
}

// ---------------- GEMM2: out = o @ w_out + b_out (fp32 out) ----------------
__global__ __launch_bounds__(256) void gemm_out(const u16* __restrict__ ob,
                                                const u16* __restrict__ wot,
                                                const float* __restrict__ bout,
                                                float* __restrict__ out) {
  __shared__ __align__(16) u16 smem[2 * 128 * 64];
  const f4 fzero = {0.f, 0.f, 0.f, 0.f};
  f4 acc[4][4];
#pragma unroll
  for (int i = 0; i < 4; ++i)
#pragma unroll
    for (int j = 0; j < 4; ++j) acc[i][j] = fzero;

  int m0 = blockIdx.y * 128, n0 = blockIdx.x * 128;
  gemm_mainloop(ob, wot, 1024, m0, n0, smem, smem + 128 * 64, acc);

  const int lane = threadIdx.x & 63, wave = threadIdx.x >> 6;
  const int quad = lane >> 4, ml = lane & 15;
  const int wm = (wave >> 1) * 64, wn = (wave & 1) * 64;
#pragma unroll
  for (int j = 0; j < 4; ++j) {
    int nn = n0 + wn + j * 16 + ml;
    float bias = bout[nn];
#pragma unroll
    for (int i = 0; i < 4; ++i)
#pragma unroll
      for (int r = 0; r < 4; ++r) {
        int tok = m0 + wm + i * 16 + quad * 4 + r;
        out[(size_t)tok * 1024 + nn] = acc[i][j][r] + bias;
      }
  }
}

// ---------------- flash attention v10: v9 structure + v8 softmax numerics ----------
// Round-7 postmortem: v9 failed absmax 1.04e-2. Root cause: v9's denominator summed
// UNROUNDED p while the numerator used v_cvt_pk_bf16_f32-rounded P. If cvt_pk rounds
// RTZ, the numerator carries a -2^-9 bias the denominator no longer cancels ->
// ~2e-3*|o| -> ~1e-2 at output. v8 passed because num and den used the SAME rounded
// values (bias cancels for ANY rounding mode). v10 restores exactly that invariant:
// manual half-up rounding, lsum from the rounded values (v8's bit path), cvt_pk
// removed. The Pq time-multiplex (change 1, algebraically verified: write units
// g*8+jl*4+quad <-> read units g*8+2quad,+1; same-wave DS is in-order so the
// ks-phase WAR reuse is safe) is kept:
// LDS = Ks 16K + Vs 16K + Pq 8K = 40KB -> 4 blocks/CU (16 waves, was 3).
// Pq layout: per-ml 128B region, 8B units u, swizzle u^(ml&14) (even mask -> pf
// b128 reads are contiguous; writes/reads 2-way bank aliased = free per m136).
// grid (64 bh, 16 qtiles): bh-major keeps each head's K/V on one XCD's L2.
__global__ __launch_bounds__(256, 4) void attn(const u16* __restrict__ q,
                                               const u16* __restrict__ k,
                                               const u16* __restrict__ vt,
                                               u16* __restrict__ o) {
  __shared__ __align__(16) u16 Ks[2][64 * 64];    // row=key, 8 chunks, XOR swizzle
  __shared__ __align__(16) u16 Vs[2][64 * 64];    // row=d,   cols=key, XOR swizzle
  __shared__ __align__(16) u16 Pq[4][16 * 64];    // per-wave P, per-ml 128B regions
  const int bh = blockIdx.x;
  const int b = bh >> 4, h = bh & 15;
  const int tid = threadIdx.x;
  const int wave = tid >> 6, lane = tid & 63;
  const int quad = lane >> 4, ml = lane & 15;
  const int qw = blockIdx.y * 128 + wave * 32;
  const u16* qp = q + (size_t)bh * 2048 * 64;
  const u16* kp = k + (size_t)bh * 2048 * 64;
  const u16* vp = vt + (size_t)bh * 64 * 2048;
  const f4 fzero = {0.f, 0.f, 0.f, 0.f};

  const int mlx = ml & 7;    // XOR bits for Ks/Vs 16B-chunk swizzle
  const int mlsw = ml & 14;  // XOR bits for Pq 8B-unit swizzle (even -> reads contiguous)

  // Q fragments: B-operand, rows qw+g*16+ml, 16B contiguous
  bh8 qf[2][2];
#pragma unroll
  for (int g = 0; g < 2; ++g)
#pragma unroll
    for (int ks = 0; ks < 2; ++ks)
      qf[g][ks] = *(const bh8*)&qp[(size_t)(qw + g * 16 + ml) * 64 + ks * 32 + quad * 8];

  f4 oacc[2][4];
#pragma unroll
  for (int g = 0; g < 2; ++g)
#pragma unroll
    for (int j = 0; j < 4; ++j) oacc[g][j] = fzero;
  float lsum[2] = {0.f, 0.f};

  // staging addresses (row/chunk decomposition identical to gemm_mainloop)
  const int srow = tid >> 3, scc = tid & 7;
  const int scg = scc ^ (srow & 7);
  u16* pq = &Pq[wave][ml * 64];   // this lane's 128B region (both g, one ks-half)

  // prologue: stage K+V tile 0 into buffer 0
#pragma unroll
  for (int r = 0; r < 2; ++r) {
    int row = r * 32 + srow;
    GLD16(kp + (size_t)row * 64 + scg * 8, &Ks[0][(row * 8 + scc) * 8]);
    GLD16(vp + (size_t)row * 2048 + scg * 8, &Vs[0][(row * 8 + scc) * 8]);
  }
  __syncthreads();

  int cur = 0;
#pragma unroll 1
  for (int t = 0; t < 32; ++t) {
    // stage next K+V tile into the other buffer (in flight until end-of-tile drain)
    if (t < 31) {
      int ktn = (t + 1) * 64;
#pragma unroll
      for (int r = 0; r < 2; ++r) {
        int row = r * 32 + srow;
        GLD16(kp + (size_t)(ktn + row) * 64 + scg * 8, &Ks[cur ^ 1][(row * 8 + scc) * 8]);
        GLD16(vp + (size_t)row * 2048 + ktn + scg * 8, &Vs[cur ^ 1][(row * 8 + scc) * 8]);
      }
    }

    // S^T = K @ Q^T from LDS: s[g][j][r] = S[q=qw+g*16+ml][kt + 16j + 4quad + r]
    f4 s[2][4];
#pragma unroll
    for (int g = 0; g < 2; ++g)
#pragma unroll
      for (int j = 0; j < 4; ++j) s[g][j] = fzero;
#pragma unroll
    for (int ks = 0; ks < 2; ++ks) {
      int cs = (ks * 4 + quad) ^ mlx;
      bh8 kf[4];
#pragma unroll
      for (int j = 0; j < 4; ++j)
        kf[j] = *(const bh8*)(&Ks[cur][((j * 16 + ml) * 8 + cs) * 8]);
#pragma unroll
      for (int j = 0; j < 4; ++j) {
        s[0][j] = __builtin_amdgcn_mfma_f32_16x16x32_bf16(kf[j], qf[0][ks], s[0][j], 0, 0, 0);
        s[1][j] = __builtin_amdgcn_mfma_f32_16x16x32_bf16(kf[j], qf[1][ks], s[1][j], 0, 0, 0);
      }
    }

    // two ks-phases: softmax keys [32ks,32ks+32) -> write -> pf read -> PV.
    // Pq slots are reused across phases (same-wave DS in-order => WAR safe).
#pragma unroll
    for (int ks = 0; ks < 2; ++ks) {
      // p = exp2(s) -> bf16 (half-up, v8 bit path); lsum from the SAME rounded
      // values so numerator/denominator rounding bias cancels exactly.
#pragma unroll
      for (int g = 0; g < 2; ++g) {
#pragma unroll
        for (int jl = 0; jl < 2; ++jl) {
          int j = ks * 2 + jl;
          uint32_t w[4];
#pragma unroll
          for (int r = 0; r < 4; ++r) {
            float p = fast_exp2(s[g][j][r]);
            union { float f; uint32_t u; } c; c.f = p;
            c.u = (c.u + 0x8000u) & 0xFFFF0000u;
            lsum[g] += c.f;
            w[r] = c.u;
          }
          uint2 pk;
          pk.x = (w[0] >> 16) | w[1];
          pk.y = (w[2] >> 16) | w[3];
          int u = g * 8 + jl * 4 + quad;            // 8B unit: keys-in-half 16jl+4quad+r
          *(uint2*)(pq + ((u ^ mlsw) << 2)) = pk;
        }
      }

      // O^T += V^T @ P^T: vf from LDS (read once per ks, reused for both groups);
      // pf = one contiguous b128 per g (keys-in-half 8quad..8quad+7).
      int cs = (ks * 4 + quad) ^ mlx;
      bh8 vf[4];
#pragma unroll
      for (int j = 0; j < 4; ++j)
        vf[j] = *(const bh8*)(&Vs[cur][((j * 16 + ml) * 8 + cs) * 8]);
#pragma unroll
      for (int g = 0; g < 2; ++g) {
        int u = g * 8 + 2 * quad;
        bh8 pf = *(const bh8*)(pq + ((u ^ mlsw) << 2));
#pragma unroll
        for (int j = 0; j < 4; ++j)
          oacc[g][j] = __builtin_amdgcn_mfma_f32_16x16x32_bf16(vf[j], pf, oacc[g][j], 0, 0, 0);
      }
    }
    __syncthreads();   // drains K/V stage (vmcnt) + all LDS reads of buf[cur]
    cur ^= 1;
  }

  // li: lane-local partial covers keys {16j+4quad+r}; reduce across quads
#pragma unroll
  for (int g = 0; g < 2; ++g) {
    lsum[g] += __shfl_xor(lsum[g], 16, 64);
    lsum[g] += __shfl_xor(lsum[g], 32, 64);
    float inv = 1.0f / lsum[g];
    // store o as (b, l, h, d) bf16; lane holds q=qw+g*16+ml, d=16j+4quad+r
    size_t obase = (((size_t)b * 2048 + qw + g * 16 + ml) * 16 + h) * 64;
#pragma unroll
    for (int j = 0; j < 4; ++j) {
      ushort4 w;
      w.x = f2bf(oacc[g][j][0] * inv);
      w.y = f2bf(oacc[g][j][1] * inv);
      w.z = f2bf(oacc[g][j][2] * inv);
      w.w = f2bf(oacc[g][j][3] * inv);
      *(ushort4*)(o + obase + j * 16 + quad * 4) = w;
    }
  }
}

// ---------------- launch ----------------

extern "C" void kernel_launch(void* const* d_in, const int* in_sizes, int n_in,
                              void* d_out, int out_size, void* d_ws, size_t ws_size,
                              hipStream_t stream) {
  const float* x     = (const float*)d_in[0];
  const float* w_qkv = (const float*)d_in[1];
  const float* b_qkv = (const float*)d_in[2];
  const float* w_out = (const float*)d_in[3];
  const float* b_out = (const float*)d_in[4];
  float* out = (float*)d_out;

  u16* ws  = (u16*)d_ws;
  u16* xb  = ws;                                  // 8192*1024 (later reused for vt)
  u16* wqt = xb + (size_t)8192 * 1024;            // 3072*1024
  u16* wot = wqt + (size_t)3072 * 1024;           // 1024*1024
  u16* qb  = wot + (size_t)1024 * 1024;           // 64*2048*64
  u16* kb  = qb + (size_t)64 * 2048 * 64;
  u16* vb  = kb + (size_t)64 * 2048 * 64;
  u16* vtb = xb;   // xb dead after gemm_qkv
  u16* ob  = vb;   // v dead after transpose_b16

  cvt_f32_bf16<<<8192, 256, 0, stream>>>(x, xb, 8192 * 1024 / 4);
  transpose_cvt<<<dim3(96, 32), dim3(32, 32), 0, stream>>>(w_qkv, wqt, 1024, 3072);
  transpose_cvt<<<dim3(32, 32), dim3(32, 32), 0, stream>>>(w_out, wot, 1024, 1024);
  gemm_qkv<<<dim3(24, 64), 256, 0, stream>>>(xb, wqt, b_qkv, qb, kb, vb);
  transpose_b16<<<dim3(2, 64, 64), dim3(32, 32), 0, stream>>>(vb, vtb);
  attn<<<dim3(64, 16), 256, 0, stream>>>(qb, kb, vtb, ob);
  gemm_out<<<dim3(8, 64), 256, 0, stream>>>(ob, wot, b_out, out);
}